// Round 13
// baseline (17.841 us; speedup 1.0000x reference)
//
#include <hip/hip_runtime.h>
#include <math.h>

// MinusAttention: score(i,j) = (w.q_i - w.k_j + b)/sqrt(E), causal softmax, @V.
// Softmax cancels the per-row (w.q_i + b) constant -> weights depend only on keys:
//   out[i] = prefix_{j<=i}(e_j * v_j) / prefix_{j<=i}(e_j),  e_j = exp(-(w.k_j)/8).
// Two kernels (rounds 3/5/7: ANY intra-kernel cross-block sync measured 2-12x
// worse than a 2nd launch). Ladder: CS=32 19.7 -> CS=64 17.1 -> CS=128 15.8 -> 256.
//   K1: chunk (256 rows) scores + chunk partial sums. Early V loads, NT key loads.
//   K2: one-record prefix per wave + register V downsweep + NT out.
// 256 blocks x 512 threads (8 waves) -> 1 block/CU.

#define B_   4
#define S_   2048
#define H_   8
#define E_   64
#define BH_  (B_ * H_)
#define CS   256                 // rows per chunk (per block)
#define NC   (S_ / CS)           // 8 chunks per (b,h)
#define NBLK (BH_ * NC)          // 256 blocks
#define TPB  512                 // 8 waves
#define WPB  8
#define RPW  32                  // rows per wave in downsweep (CS / WPB)

typedef float v4f __attribute__((ext_vector_type(4)));

// ---------------- K1: scores + chunk partials ----------------
__global__ __launch_bounds__(TPB) void k_part(const float* __restrict__ keys,
                                              const float* __restrict__ values,
                                              const float* __restrict__ w,
                                              float* __restrict__ e_g,
                                              float* __restrict__ cden,
                                              float* __restrict__ cnum) {
    const int blk = blockIdx.x;
    const int bh  = blk / NC, c = blk % NC;
    const int b   = bh / H_,  h = bh % H_;
    const int t   = threadIdx.x, wave = t >> 6, lane = t & 63;
    const int cf  = lane & 15, rq = lane >> 4;
    const int c4  = t & 15,   rg = t >> 4;     // value-load pattern (32 row-groups)

    __shared__ float e_lds[CS];
    __shared__ float red[32][E_];              // row-group partials, 8KB

    const size_t row0 = (size_t)b * S_ + (size_t)c * CS;

    // T14: issue the 8 independent V float4 streams FIRST (latency hides under
    // key dots). Rows rg+32k, float4 column c4. Cached — K2 re-reads them.
    const v4f* vb = reinterpret_cast<const v4f*>(
        values + (row0 * H_ + h) * (size_t)E_) + c4;
    v4f v_s[8];
    #pragma unroll
    for (int k = 0; k < 8; ++k)
        v_s[k] = vb[(size_t)(rg + 32 * k) * (H_ * E_ / 4)];

    // scores: wave w covers rows w*32 .. w*32+31; e = exp(-(w.k)/8).
    // Keys are read-once -> non-temporal (preserve L2/L3 for values).
    const float4 w4 = reinterpret_cast<const float4*>(w)[cf];
    const float* kb = keys + (row0 * H_ + h) * (size_t)E_;
    #pragma unroll
    for (int g = 0; g < 8; ++g) {
        const int r = wave * RPW + g * 4 + rq;
        const v4f kv = __builtin_nontemporal_load(
            reinterpret_cast<const v4f*>(kb + (size_t)r * (H_ * E_)) + cf);
        float p = kv.x * w4.x + kv.y * w4.y + kv.z * w4.z + kv.w * w4.w;
        p += __shfl_xor(p, 1);
        p += __shfl_xor(p, 2);
        p += __shfl_xor(p, 4);
        p += __shfl_xor(p, 8);
        if (cf == 0) e_lds[r] = __expf(-p * 0.125f);
    }
    __syncthreads();

    // weighted rows: acc = sum_k e[rg+32k] * v_s[k]
    v4f acc = {0.f, 0.f, 0.f, 0.f};
    #pragma unroll
    for (int k = 0; k < 8; ++k) {
        const float e = e_lds[rg + 32 * k];
        acc.x = fmaf(e, v_s[k].x, acc.x);
        acc.y = fmaf(e, v_s[k].y, acc.y);
        acc.z = fmaf(e, v_s[k].z, acc.z);
        acc.w = fmaf(e, v_s[k].w, acc.w);
    }
    *reinterpret_cast<v4f*>(&red[rg][c4 * 4]) = acc;

    // den: wave 0 reduces the 256 e values (4 per lane, then 64-lane butterfly)
    if (wave == 0) {
        float d = e_lds[lane] + e_lds[lane + 64] +
                  e_lds[lane + 128] + e_lds[lane + 192];
        d += __shfl_xor(d, 1);
        d += __shfl_xor(d, 2);
        d += __shfl_xor(d, 4);
        d += __shfl_xor(d, 8);
        d += __shfl_xor(d, 16);
        d += __shfl_xor(d, 32);
        if (lane == 0) cden[blk] = d;
    }
    __syncthreads();

    if (t < E_) {                              // channel-wise reduce over 32 rg
        float s = 0.f;
        #pragma unroll
        for (int r2 = 0; r2 < 32; ++r2) s += red[r2][t];
        cnum[(size_t)blk * E_ + t] = s;
    }
    // e_g: 256 floats, all 512 threads -> first 256
    if (t < CS) e_g[(size_t)blk * CS + t] = e_lds[t];
}

// ---------------- K2: prefix + register downsweep + out ----------------
__global__ __launch_bounds__(TPB) void k_scan(const float* __restrict__ values,
                                              const float* __restrict__ e_g,
                                              const float* __restrict__ cden,
                                              const float* __restrict__ cnum,
                                              float* __restrict__ out) {
    const int blk = blockIdx.x;
    const int bh  = blk / NC, c = blk % NC;
    const int b   = bh / H_,  h = bh % H_;
    const int t   = threadIdx.x, wave = t >> 6, lane = t & 63;

    __shared__ float e_lds[CS];
    __shared__ float pnum8[WPB][E_];
    __shared__ float wnum[WPB][E_];
    __shared__ float pd8[WPB], wd[WPB];

    const size_t row0 = (size_t)b * S_ + (size_t)c * CS;

    // T14: issue V (L2/L3-hot, 32-deep queue) + e loads first.
    const float* vp = values + ((row0 + wave * RPW) * H_ + h) * (size_t)E_ + lane;
    float v_r[RPW];
    #pragma unroll
    for (int j = 0; j < RPW; ++j) v_r[j] = vp[(size_t)j * (H_ * E_)];
    e_lds[t & (CS - 1)] = e_g[(size_t)blk * CS + (t & (CS - 1))];

    // cross-chunk exclusive prefix: c < 8 predecessors, one per wave (<=1 iter)
    const int base = bh * NC;
    float pn = 0.f, pd = 0.f;
    if (wave < c) {
        pn = cnum[(size_t)(base + wave) * E_ + lane];   // 256B coalesced
        pd = cden[base + wave];                         // uniform
    }
    pnum8[wave][lane] = pn;
    if (lane == 0) pd8[wave] = pd;
    __syncthreads();

    // per-wave partials: wave w owns rows w*32 .. w*32+31
    float num = 0.f, den = 0.f;
    #pragma unroll
    for (int j = 0; j < RPW; ++j) {
        const float e = e_lds[wave * RPW + j];
        num = fmaf(e, v_r[j], num);
        den += e;
    }
    wnum[wave][lane] = num;
    if (lane == 0) wd[wave] = den;
    __syncthreads();

    // combine cross-chunk + cross-wave offsets
    float pnum = 0.f, pden = 0.f;
    #pragma unroll
    for (int i = 0; i < WPB; ++i) { pnum += pnum8[i][lane]; pden += pd8[i]; }
    #pragma unroll
    for (int w2 = 0; w2 < WPB - 1; ++w2) {
        if (w2 < wave) { pnum += wnum[w2][lane]; pden += wd[w2]; }
    }

    // downsweep from registers, NT store (out is write-once)
    float* op = out + ((row0 + wave * RPW) * H_ + h) * (size_t)E_ + lane;  // L==S
    #pragma unroll
    for (int j = 0; j < RPW; ++j) {
        const float e = e_lds[wave * RPW + j];
        pnum = fmaf(e, v_r[j], pnum);
        pden += e;
        __builtin_nontemporal_store(pnum * __builtin_amdgcn_rcpf(pden),
                                    &op[(size_t)j * (H_ * E_)]);
    }
}

extern "C" void kernel_launch(void* const* d_in, const int* in_sizes, int n_in,
                              void* d_out, int out_size, void* d_ws, size_t ws_size,
                              hipStream_t stream) {
    // inputs: 0=queries (UNUSED), 1=keys, 2=values, 3=w_score,
    //         4=b_score (cancels), 5=attn_mask (sentinel -> causal)
    const float* keys   = (const float*)d_in[1];
    const float* values = (const float*)d_in[2];
    const float* w      = (const float*)d_in[3];
    float* out = (float*)d_out;

    // workspace (floats): e_g[NBLK*CS] | cnum[NBLK*E] | cden[NBLK]
    float* e_g  = (float*)d_ws;
    float* cnum = e_g + (size_t)NBLK * CS;
    float* cden = cnum + (size_t)NBLK * E_;

    hipLaunchKernelGGL(k_part, dim3(NBLK), dim3(TPB), 0, stream,
                       keys, values, w, e_g, cden, cnum);
    hipLaunchKernelGGL(k_scan, dim3(NBLK), dim3(TPB), 0, stream,
                       values, e_g, cden, cnum, out);
}

// Round 14
// 15.908 us; speedup vs baseline: 1.1215x; 1.1215x over previous
//
#include <hip/hip_runtime.h>
#include <math.h>

// MinusAttention: score(i,j) = (w.q_i - w.k_j + b)/sqrt(E), causal softmax, @V.
// Softmax cancels the per-row (w.q_i + b) constant -> weights depend only on keys:
//   out[i] = prefix_{j<=i}(e_j * v_j) / prefix_{j<=i}(e_j),  e_j = exp(-(w.k_j)/8).
// Two kernels (rounds 3/5/7: ANY intra-kernel cross-block sync measured 2-12x
// worse than a 2nd launch). Chunk ladder: CS=32 19.7 -> 64 17.1 -> 128 15.8
// -> 256 17.8 (regressed: <16 waves/CU loses latency hiding). CS=128 is optimal.
//   K1: chunk (128 rows) scores + chunk partial sums. Early V loads, NT key loads.
//   K2: wave-strided prefix over predecessors + register V downsweep + NT out.
// 512 blocks x 512 threads (8 waves) -> 2 blocks/CU, 16 waves/CU.

#define B_   4
#define S_   2048
#define H_   8
#define E_   64
#define BH_  (B_ * H_)
#define CS   128                 // rows per chunk (per block)
#define NC   (S_ / CS)           // 16 chunks per (b,h)
#define NBLK (BH_ * NC)          // 512 blocks
#define TPB  512                 // 8 waves
#define WPB  8
#define RPW  16                  // rows per wave in downsweep (CS / WPB)

typedef float v4f __attribute__((ext_vector_type(4)));

// ---------------- K1: scores + chunk partials ----------------
__global__ __launch_bounds__(TPB) void k_part(const float* __restrict__ keys,
                                              const float* __restrict__ values,
                                              const float* __restrict__ w,
                                              float* __restrict__ e_g,
                                              float* __restrict__ cden,
                                              float* __restrict__ cnum) {
    const int blk = blockIdx.x;
    const int bh  = blk / NC, c = blk % NC;
    const int b   = bh / H_,  h = bh % H_;
    const int t   = threadIdx.x, wave = t >> 6, lane = t & 63;
    const int cf  = lane & 15, rq = lane >> 4;
    const int c4  = t & 15,   rg = t >> 4;     // value-load pattern (32 row-groups)

    __shared__ float e_lds[CS];
    __shared__ float red[32][E_];              // row-group partials, 8KB

    const size_t row0 = (size_t)b * S_ + (size_t)c * CS;

    // T14: issue the 4 independent V float4 streams FIRST (latency hides under
    // key dots). Rows rg+32k, float4 column c4. Cached — K2 re-reads them.
    const v4f* vb = reinterpret_cast<const v4f*>(
        values + (row0 * H_ + h) * (size_t)E_) + c4;
    v4f v0 = vb[(size_t)(rg     ) * (H_ * E_ / 4)];
    v4f v1 = vb[(size_t)(rg + 32) * (H_ * E_ / 4)];
    v4f v2 = vb[(size_t)(rg + 64) * (H_ * E_ / 4)];
    v4f v3 = vb[(size_t)(rg + 96) * (H_ * E_ / 4)];

    // scores: wave w covers rows w*16 .. w*16+15; e = exp(-(w.k)/8).
    // Keys are read-once -> non-temporal (preserve L2/L3 for values).
    const float4 w4 = reinterpret_cast<const float4*>(w)[cf];
    const float* kb = keys + (row0 * H_ + h) * (size_t)E_;
    #pragma unroll
    for (int g = 0; g < 4; ++g) {
        const int r = wave * RPW + g * 4 + rq;
        const v4f kv = __builtin_nontemporal_load(
            reinterpret_cast<const v4f*>(kb + (size_t)r * (H_ * E_)) + cf);
        float p = kv.x * w4.x + kv.y * w4.y + kv.z * w4.z + kv.w * w4.w;
        p += __shfl_xor(p, 1);
        p += __shfl_xor(p, 2);
        p += __shfl_xor(p, 4);
        p += __shfl_xor(p, 8);
        if (cf == 0) e_lds[r] = __expf(-p * 0.125f);
    }
    __syncthreads();

    // weighted rows: acc = sum_k e[rg+32k] * vk
    const float e0 = e_lds[rg],      e1 = e_lds[rg + 32];
    const float e2 = e_lds[rg + 64], e3 = e_lds[rg + 96];
    v4f acc;
    acc.x = fmaf(e3, v3.x, fmaf(e2, v2.x, fmaf(e1, v1.x, e0 * v0.x)));
    acc.y = fmaf(e3, v3.y, fmaf(e2, v2.y, fmaf(e1, v1.y, e0 * v0.y)));
    acc.z = fmaf(e3, v3.z, fmaf(e2, v2.z, fmaf(e1, v1.z, e0 * v0.z)));
    acc.w = fmaf(e3, v3.w, fmaf(e2, v2.w, fmaf(e1, v1.w, e0 * v0.w)));
    *reinterpret_cast<v4f*>(&red[rg][c4 * 4]) = acc;

    // den: wave 0 reduces the 128 e values (2 per lane, then 64-lane butterfly)
    if (wave == 0) {
        float d = e_lds[lane] + e_lds[lane + 64];
        d += __shfl_xor(d, 1);
        d += __shfl_xor(d, 2);
        d += __shfl_xor(d, 4);
        d += __shfl_xor(d, 8);
        d += __shfl_xor(d, 16);
        d += __shfl_xor(d, 32);
        if (lane == 0) cden[blk] = d;
    }
    __syncthreads();

    // two-stage channel reduce over 32 row-groups (all 8 waves in stage 1).
    // Wave w reads rows 4w..4w+3 and writes row 4w — disjoint, no extra barrier.
    const float s4 = red[wave * 4 + 0][lane] + red[wave * 4 + 1][lane] +
                     red[wave * 4 + 2][lane] + red[wave * 4 + 3][lane];
    red[wave * 4][lane] = s4;
    __syncthreads();
    if (t < E_) {
        float s = 0.f;
        #pragma unroll
        for (int r2 = 0; r2 < 8; ++r2) s += red[r2 * 4][t];
        cnum[(size_t)blk * E_ + t] = s;
    }
    if (t < CS) e_g[(size_t)blk * CS + t] = e_lds[t];
}

// ---------------- K2: prefix + register downsweep + out ----------------
__global__ __launch_bounds__(TPB) void k_scan(const float* __restrict__ values,
                                              const float* __restrict__ e_g,
                                              const float* __restrict__ cden,
                                              const float* __restrict__ cnum,
                                              float* __restrict__ out) {
    const int blk = blockIdx.x;
    const int bh  = blk / NC, c = blk % NC;
    const int b   = bh / H_,  h = bh % H_;
    const int t   = threadIdx.x, wave = t >> 6, lane = t & 63;

    __shared__ float e_lds[CS];
    __shared__ float pnum8[WPB][E_];
    __shared__ float wnum[WPB][E_];
    __shared__ float pd8[WPB], wd[WPB];

    const size_t row0 = (size_t)b * S_ + (size_t)c * CS;

    // T14: issue V (L2/L3-hot, 16-deep queue) + e loads first.
    const float* vp = values + ((row0 + wave * RPW) * H_ + h) * (size_t)E_ + lane;
    float v_r[RPW];
    #pragma unroll
    for (int j = 0; j < RPW; ++j) v_r[j] = vp[(size_t)j * (H_ * E_)];
    if (t < CS) e_lds[t] = e_g[(size_t)blk * CS + t];

    // cross-chunk exclusive prefix, wave-strided over predecessors (L2-hot)
    const int base = bh * NC;
    float pn = 0.f, pd = 0.f;
    for (int cp = wave; cp < c; cp += WPB) {
        pn += cnum[(size_t)(base + cp) * E_ + lane];   // 256B coalesced
        pd += cden[base + cp];                         // uniform
    }
    pnum8[wave][lane] = pn;
    if (lane == 0) pd8[wave] = pd;
    __syncthreads();

    // per-wave partials: wave w owns rows w*16 .. w*16+15
    float num = 0.f, den = 0.f;
    #pragma unroll
    for (int j = 0; j < RPW; ++j) {
        const float e = e_lds[wave * RPW + j];
        num = fmaf(e, v_r[j], num);
        den += e;
    }
    wnum[wave][lane] = num;
    if (lane == 0) wd[wave] = den;
    __syncthreads();

    // combine cross-chunk + cross-wave offsets
    float pnum = 0.f, pden = 0.f;
    #pragma unroll
    for (int i = 0; i < WPB; ++i) { pnum += pnum8[i][lane]; pden += pd8[i]; }
    #pragma unroll
    for (int w2 = 0; w2 < WPB - 1; ++w2) {
        if (w2 < wave) { pnum += wnum[w2][lane]; pden += wd[w2]; }
    }

    // downsweep from registers, NT store (out is write-once)
    float* op = out + ((row0 + wave * RPW) * H_ + h) * (size_t)E_ + lane;  // L==S
    #pragma unroll
    for (int j = 0; j < RPW; ++j) {
        const float e = e_lds[wave * RPW + j];
        pnum = fmaf(e, v_r[j], pnum);
        pden += e;
        __builtin_nontemporal_store(pnum * __builtin_amdgcn_rcpf(pden),
                                    &op[(size_t)j * (H_ * E_)]);
    }
}

extern "C" void kernel_launch(void* const* d_in, const int* in_sizes, int n_in,
                              void* d_out, int out_size, void* d_ws, size_t ws_size,
                              hipStream_t stream) {
    // inputs: 0=queries (UNUSED), 1=keys, 2=values, 3=w_score,
    //         4=b_score (cancels), 5=attn_mask (sentinel -> causal)
    const float* keys   = (const float*)d_in[1];
    const float* values = (const float*)d_in[2];
    const float* w      = (const float*)d_in[3];
    float* out = (float*)d_out;

    // workspace (floats): e_g[NBLK*CS] | cnum[NBLK*E] | cden[NBLK]
    float* e_g  = (float*)d_ws;
    float* cnum = e_g + (size_t)NBLK * CS;
    float* cden = cnum + (size_t)NBLK * E_;

    hipLaunchKernelGGL(k_part, dim3(NBLK), dim3(TPB), 0, stream,
                       keys, values, w, e_g, cden, cnum);
    hipLaunchKernelGGL(k_scan, dim3(NBLK), dim3(TPB), 0, stream,
                       values, e_g, cden, cnum, out);
}